// Round 12
// baseline (149.798 us; speedup 1.0000x reference)
//
#include <hip/hip_runtime.h>
#include <hip/hip_bf16.h>
#include <math.h>

#define N_NODES 1024
#define T_DIM 8

typedef __bf16 bf16x8 __attribute__((ext_vector_type(8)));
typedef float  f32x4  __attribute__((ext_vector_type(4)));

__device__ __forceinline__ float readlane_f(float v, int l) {
    return __uint_as_float(__builtin_amdgcn_readlane(__float_as_uint(v), l));
}

// ---- Kernel A (fused): h=inp@W ; s1,s2 ; hF tiles ; adjT permute (coalesced) -
__global__ __launch_bounds__(256) void gat_h_kernel(
    const float* __restrict__ inp, const float* __restrict__ W,
    const float* __restrict__ a, const float* __restrict__ att_mask,
    const float* __restrict__ adj, float* __restrict__ adjT,
    __bf16* __restrict__ hF, float* __restrict__ s1w, float* __restrict__ s2w)
{
    __shared__ float Wl[64 * 64];
    __shared__ float xl[64 * 64];
    __shared__ __bf16 htl[64 * 72];   // [o][j], stride 72

    const int tid  = threadIdx.x;
    const int blk  = blockIdx.x;
    const int bt   = blk >> 4;
    const int b    = bt >> 3;
    const int t    = bt & 7;
    const int nt   = blk & 15;        // j-tile
    const int n0   = nt * 64;
    const int lane = tid & 63;        // = o in compute phase
    const int wave = tid >> 6;

    const float4* W4  = (const float4*)W;
    float4*       Wl4 = (float4*)Wl;
    const float4* x4  = (const float4*)(inp + (size_t)(bt * N_NODES + n0) * 64);
    float4*       xl4 = (float4*)xl;
#pragma unroll
    for (int k = 0; k < 4; ++k) {
        Wl4[tid + k * 256] = W4[tid + k * 256];
        xl4[tid + k * 256] = x4[tid + k * 256];
    }
    const float a1 = a[lane];
    const float a2 = a[64 + lane];
    __syncthreads();

#pragma unroll 1
    for (int rg = 0; rg < 16; rg += 4) {
        float xr[4], acc[4];
#pragma unroll
        for (int q = 0; q < 4; ++q) {
            xr[q]  = xl[(wave * 16 + rg + q) * 64 + lane];
            acc[q] = 0.f;
        }
#pragma unroll
        for (int f = 0; f < 64; ++f) {
            float w = Wl[f * 64 + lane];
#pragma unroll
            for (int q = 0; q < 4; ++q)
                acc[q] = fmaf(readlane_f(xr[q], f), w, acc[q]);
        }
#pragma unroll
        for (int q = 0; q < 4; ++q) {
            const int r = wave * 16 + rg + q;   // local j
            float v1 = acc[q] * a1, v2 = acc[q] * a2;
#pragma unroll
            for (int off = 32; off; off >>= 1) {
                v1 += __shfl_xor(v1, off, 64);
                v2 += __shfl_xor(v2, off, 64);
            }
            if (lane == 0) {
                s1w[bt * N_NODES + n0 + r] = v1;
                s2w[bt * N_NODES + n0 + r] = v2;
            }
            const float mjr = att_mask[((size_t)b * N_NODES + n0 + r) * T_DIM + t];
            htl[lane * 72 + r] = (__bf16)(acc[q] * mjr);   // [o][j]
        }
    }
    __syncthreads();

    // hF write: B-frag-ordered chunks (unchanged, validated r10/r11)
    {
        const int l  = tid & 63;
        const int w  = tid >> 6;
        __bf16* tbase = hF + (size_t)(bt * 16 + nt) * 4096;
#pragma unroll
        for (int cc = 0; cc < 2; ++cc) {
            const int c  = w + cc * 4;       // chunk = kc*4 + nc
            const int nc = c & 3;
            const int kc = c >> 2;
            bf16x8 v = *(const bf16x8*)&htl[(nc * 16 + (l & 15)) * 72
                                            + (l >> 4) * 8 + kc * 32];
            *(bf16x8*)(tbase + (c * 64 + l) * 8) = v;
        }
    }

    // ---- Phase 2: adj permute, COALESCED reads (256 thr = one 4KB row),
    // frag-order scatter on the write side (fire-and-forget stores).
    // adjT[tile jt][ (quad*16+r)*16 + kc*8 + m ] = adj[t][i0+r][jt*64+kc*32+quad*8+m]
    {
        const int itile = b * 16 + nt;     // each (t,itile) covered exactly once
        const int i0    = itile * 16;
        const float* srcb = adj + (size_t)t * N_NODES * N_NODES + (size_t)i0 * N_NODES;
        float* dstb = adjT + (size_t)(t * 64 + itile) * 16 * 1024;
        const int c0   = tid * 4;          // column group, full 1024-row per pass
        const int jt   = c0 >> 6;
        const int j6   = c0 & 63;
        const int kc   = j6 >> 5;
        const int quad = (j6 >> 3) & 3;
        const int m0   = j6 & 7;           // 0 or 4
        float* dcol = dstb + (size_t)jt * 1024 + quad * 256 + kc * 8 + m0;
#pragma unroll
        for (int r = 0; r < 16; ++r) {
            f32x4 v = *(const f32x4*)(srcb + (size_t)r * N_NODES + c0);
            *(f32x4*)(dcol + r * 16) = v;
        }
    }
}

// ---- Kernel B: j-split partial flash GAT, 4 independent waves/block ---------
// grid (64 itile, 32 bt) x 256 thr. Wave js owns j in [js*256, js*256+256)
// (4 tiles of 64), accumulates a partial 16x64 C-tile + partial lsum, writes
// them to ws. 8192 waves (~28-32/CU) vs 2048 in all prior rounds — the grid
// was the occupancy limiter. All frag reads contiguous (r10 layout); no LDS,
// no barriers, no in-loop shuffles; 1-tile register prefetch, phase stagger.
__global__ __launch_bounds__(256) void gat_attn_kernel(
    const float* __restrict__ adjT, const __bf16* __restrict__ hF,
    const float* __restrict__ s1w, const float* __restrict__ s2w,
    float* __restrict__ pacc, float* __restrict__ plsum)
{
    const int bt    = blockIdx.y;
    const int t     = bt & 7;
    const int itile = blockIdx.x;
    const int irow0 = itile * 16;
    const int tid   = threadIdx.x;
    const int lane  = tid & 63;
    const int js    = tid >> 6;         // wave = j-quarter
    const int l15   = lane & 15;
    const int quad  = lane >> 4;
    const int phase = itile & 3;        // stagger within the quarter

    f32x4 acc[4];
#pragma unroll
    for (int nc = 0; nc < 4; ++nc) acc[nc] = (f32x4){0.f, 0.f, 0.f, 0.f};
    float lsum = 0.f;
    const float s1r = s1w[bt * N_NODES + irow0 + l15];

    const float*  atb = adjT + (size_t)(t * 64 + itile) * 16 * 1024 + lane * 16;
    const __bf16* htb = hF + (size_t)bt * 16 * 4096 + lane * 8;
    const float*  s2p = s2w + bt * N_NODES + quad * 8;

    // ---- preload tile js*4+phase ----
    f32x4  adjc[4], s2c[4];
    bf16x8 hc[8];
    {
        const int jt = js * 4 + phase;
        const float* ap = atb + (size_t)jt * 1024;
#pragma unroll
        for (int k = 0; k < 4; ++k) adjc[k] = *(const f32x4*)(ap + k * 4);
#pragma unroll
        for (int k = 0; k < 2; ++k) {
            s2c[k]     = *(const f32x4*)(s2p + jt * 64 + k * 4);
            s2c[2 + k] = *(const f32x4*)(s2p + jt * 64 + 32 + k * 4);
        }
        const __bf16* hp = htb + (size_t)jt * 4096;
#pragma unroll
        for (int c = 0; c < 8; ++c) hc[c] = *(const bf16x8*)(hp + c * 512);
    }

#pragma unroll 2
    for (int it = 0; it < 4; ++it) {
        const int jn = js * 4 + ((it + 1 + phase) & 3);   // ring within quarter

        // ---- prefetch next tile (all lane-contiguous) ----
        f32x4  adjn[4], s2n[4];
        bf16x8 hn[8];
        {
            const float* ap = atb + (size_t)jn * 1024;
#pragma unroll
            for (int k = 0; k < 4; ++k) adjn[k] = *(const f32x4*)(ap + k * 4);
#pragma unroll
            for (int k = 0; k < 2; ++k) {
                s2n[k]     = *(const f32x4*)(s2p + jn * 64 + k * 4);
                s2n[2 + k] = *(const f32x4*)(s2p + jn * 64 + 32 + k * 4);
            }
            const __bf16* hp = htb + (size_t)jn * 4096;
#pragma unroll
            for (int c = 0; c < 8; ++c) hn[c] = *(const bf16x8*)(hp + c * 512);
        }

        // ---- scores in A-frag register order; leaky bounds e*adj in [-6,~16]
        // so exp never overflows -> no max pass needed ----
        const float* ac = (const float*)adjc;   // idx = kc*8 + m
        const float* sc = (const float*)s2c;
        bf16x8 af[2];
#pragma unroll
        for (int kc = 0; kc < 2; ++kc)
#pragma unroll
            for (int m = 0; m < 8; ++m) {
                float av = ac[kc * 8 + m];
                float e  = s1r + sc[kc * 8 + m];
                e = fmaxf(e, 0.2f * e);
                float p = (av > 0.f) ? __expf(e * av) : 0.f;
                lsum += p;
                af[kc][m] = (__bf16)p;
            }

        // ---- 8 MFMAs ----
#pragma unroll
        for (int nc = 0; nc < 4; ++nc)
            acc[nc] = __builtin_amdgcn_mfma_f32_16x16x32_bf16(af[0], hc[nc], acc[nc], 0, 0, 0);
#pragma unroll
        for (int nc = 0; nc < 4; ++nc)
            acc[nc] = __builtin_amdgcn_mfma_f32_16x16x32_bf16(af[1], hc[4 + nc], acc[nc], 0, 0, 0);

        // ---- rotate prefetch buffers ----
#pragma unroll
        for (int k = 0; k < 4; ++k) { adjc[k] = adjn[k]; s2c[k] = s2n[k]; }
#pragma unroll
        for (int c = 0; c < 8; ++c) hc[c] = hn[c];
    }

    // ---- write partial C-tile + partial lsum ----
    float* pb = pacc + ((size_t)(bt * 64 + itile) * 4 + js) * 1024;
#pragma unroll
    for (int nc = 0; nc < 4; ++nc)
#pragma unroll
        for (int reg = 0; reg < 4; ++reg)
            pb[(quad * 4 + reg) * 64 + nc * 16 + l15] = acc[nc][reg];

    lsum += __shfl_xor(lsum, 16, 64);
    lsum += __shfl_xor(lsum, 32, 64);   // lanes 0..15 hold rows 0..15 partials
    if (lane < 16)
        plsum[((size_t)(bt * 64 + itile) * 4 + js) * 16 + lane] = lsum;
}

// ---- Kernel C: sum 4 partials, mi/ls scale + ELU, coalesced store -----------
__global__ __launch_bounds__(256) void gat_reduce_kernel(
    const float* __restrict__ pacc, const float* __restrict__ plsum,
    const float* __restrict__ att_mask, float* __restrict__ out)
{
    const int itile = blockIdx.x;
    const int bt    = blockIdx.y;
    const int b     = bt >> 3;
    const int t     = bt & 7;
    const int tid   = threadIdx.x;
    const int row   = tid >> 4;          // 0..15
    const int c0    = (tid & 15) * 4;    // column group

    const float* pb = pacc + (size_t)(bt * 64 + itile) * 4096;
    f32x4 v = (f32x4){0.f, 0.f, 0.f, 0.f};
#pragma unroll
    for (int js = 0; js < 4; ++js)
        v += *(const f32x4*)(pb + js * 1024 + row * 64 + c0);

    const float* lb = plsum + (size_t)(bt * 64 + itile) * 64;
    float ls = lb[row] + lb[16 + row] + lb[32 + row] + lb[48 + row];

    const int i = itile * 16 + row;
    float mi = att_mask[((size_t)b * N_NODES + i) * T_DIM + t];
    float scale = mi / ls;
#pragma unroll
    for (int k = 0; k < 4; ++k) {
        float x = v[k] * scale;
        v[k] = (x > 0.f) ? x : (__expf(x) - 1.f);
    }
    *(f32x4*)(out + ((size_t)bt * N_NODES + i) * 64 + c0) = v;
}

extern "C" void kernel_launch(void* const* d_in, const int* in_sizes, int n_in,
                              void* d_out, int out_size, void* d_ws, size_t ws_size,
                              hipStream_t stream) {
    (void)in_sizes; (void)n_in; (void)out_size; (void)ws_size;
    const float* adj      = (const float*)d_in[0];   // (T,N,N)
    const float* inp      = (const float*)d_in[1];   // (B,T,N,FI)
    const float* att_mask = (const float*)d_in[2];   // (B,N,T)
    const float* W        = (const float*)d_in[3];   // (FI,FO)
    const float* a        = (const float*)d_in[4];   // (2*FO,1)
    float* out = (float*)d_out;

    // ws: adjT 32MB | hF 4MB | s1 128KB | s2 128KB | pacc 32MB | plsum 512KB
    float*  adjT  = (float*)d_ws;
    __bf16* hF    = (__bf16*)((char*)d_ws + (size_t)32 * 1024 * 1024);
    float*  s1w   = (float*)((char*)d_ws + (size_t)36 * 1024 * 1024);
    float*  s2w   = s1w + 32 * N_NODES;
    float*  pacc  = (float*)((char*)d_ws + (size_t)40 * 1024 * 1024);
    float*  plsum = (float*)((char*)d_ws + (size_t)72 * 1024 * 1024);

    gat_h_kernel<<<512, 256, 0, stream>>>(inp, W, a, att_mask, adj, adjT, hF, s1w, s2w);
    dim3 grid(64, 32);
    gat_attn_kernel<<<grid, 256, 0, stream>>>(adjT, hF, s1w, s2w, pacc, plsum);
    gat_reduce_kernel<<<grid, 256, 0, stream>>>(pacc, plsum, att_mask, out);
}

// Round 13
// 124.901 us; speedup vs baseline: 1.1993x; 1.1993x over previous
//
#include <hip/hip_runtime.h>
#include <hip/hip_bf16.h>
#include <math.h>

#define N_NODES 1024
#define T_DIM 8

typedef __bf16 bf16x8 __attribute__((ext_vector_type(8)));
typedef float  f32x4  __attribute__((ext_vector_type(4)));

__device__ __forceinline__ float readlane_f(float v, int l) {
    return __uint_as_float(__builtin_amdgcn_readlane(__float_as_uint(v), l));
}

// ---- Kernel A: h = inp@W ; s1,s2 ; hF = (h*mask_j) in B-frag-ordered tiles --
// hF tile (bt,jt) = 8 chunks of 1KB; chunk c=kc*4+nc, lane l, m 0..7 holds
// h[o = nc*16 + (l&15)][j = jt*64 + (l>>4)*8 + kc*32 + m] * mask_j.
// mask_j folded here (hF only feeds PV; softmax denominator is unmasked).
__global__ __launch_bounds__(256) void gat_h_kernel(
    const float* __restrict__ inp, const float* __restrict__ W,
    const float* __restrict__ a, const float* __restrict__ att_mask,
    __bf16* __restrict__ hF, float* __restrict__ s1w, float* __restrict__ s2w)
{
    __shared__ float Wl[64 * 64];
    __shared__ float xl[64 * 64];
    __shared__ __bf16 htl[64 * 72];   // [o][j], stride 72

    const int tid  = threadIdx.x;
    const int blk  = blockIdx.x;
    const int bt   = blk >> 4;
    const int b    = bt >> 3;
    const int t    = bt & 7;
    const int nt   = blk & 15;        // j-tile
    const int n0   = nt * 64;
    const int lane = tid & 63;        // = o in compute phase
    const int wave = tid >> 6;

    const float4* W4  = (const float4*)W;
    float4*       Wl4 = (float4*)Wl;
    const float4* x4  = (const float4*)(inp + (size_t)(bt * N_NODES + n0) * 64);
    float4*       xl4 = (float4*)xl;
#pragma unroll
    for (int k = 0; k < 4; ++k) {
        Wl4[tid + k * 256] = W4[tid + k * 256];
        xl4[tid + k * 256] = x4[tid + k * 256];
    }
    const float a1 = a[lane];
    const float a2 = a[64 + lane];
    __syncthreads();

#pragma unroll 1
    for (int rg = 0; rg < 16; rg += 4) {
        float xr[4], acc[4];
#pragma unroll
        for (int q = 0; q < 4; ++q) {
            xr[q]  = xl[(wave * 16 + rg + q) * 64 + lane];
            acc[q] = 0.f;
        }
#pragma unroll
        for (int f = 0; f < 64; ++f) {
            float w = Wl[f * 64 + lane];
#pragma unroll
            for (int q = 0; q < 4; ++q)
                acc[q] = fmaf(readlane_f(xr[q], f), w, acc[q]);
        }
#pragma unroll
        for (int q = 0; q < 4; ++q) {
            const int r = wave * 16 + rg + q;   // local j
            float v1 = acc[q] * a1, v2 = acc[q] * a2;
#pragma unroll
            for (int off = 32; off; off >>= 1) {
                v1 += __shfl_xor(v1, off, 64);
                v2 += __shfl_xor(v2, off, 64);
            }
            if (lane == 0) {
                s1w[bt * N_NODES + n0 + r] = v1;
                s2w[bt * N_NODES + n0 + r] = v2;
            }
            const float mjr = att_mask[((size_t)b * N_NODES + n0 + r) * T_DIM + t];
            htl[lane * 72 + r] = (__bf16)(acc[q] * mjr);   // [o][j]
        }
    }
    __syncthreads();

    // hF write: B-frag-ordered chunks (validated r10-r12)
    {
        const int l  = tid & 63;
        const int w  = tid >> 6;
        __bf16* tbase = hF + (size_t)(bt * 16 + nt) * 4096;
#pragma unroll
        for (int cc = 0; cc < 2; ++cc) {
            const int c  = w + cc * 4;       // chunk = kc*4 + nc
            const int nc = c & 3;
            const int kc = c >> 2;
            bf16x8 v = *(const bf16x8*)&htl[(nc * 16 + (l & 15)) * 72
                                            + (l >> 4) * 8 + kc * 32];
            *(bf16x8*)(tbase + (c * 64 + l) * 8) = v;
        }
    }
}

// ---- Kernel B: one-wave flash GAT — coalesced adj + contiguous hF frags -----
// grid (64 i-tiles, 32 bt) x 64 thr. Wave owns 16 rows, 16 j-tiles.
// Line-count budget per iter: adj = 16 coalesced 256B row loads (64 lines,
// irreducible), h = 8 contiguous 1KB loads (32 lines — was 128 as gathers in
// r9: the dominant L1/TA request stream halved). P via wave-private LDS
// (16 b16 writes + 2 b128 reads, 2-way banks = free). Phase stagger itile&15
// de-correlates i-blocks while keeping b-siblings aligned for adj L3 reuse.
// No barriers, no in-loop shuffles; 1-tile register prefetch.
__global__ __launch_bounds__(64) void gat_attn_kernel(
    const float* __restrict__ adj, const float* __restrict__ att_mask,
    const __bf16* __restrict__ hF, const float* __restrict__ s1w,
    const float* __restrict__ s2w, float* __restrict__ out)
{
    __shared__ __align__(16) __bf16 p_l[16 * 72];   // [row][j], pad 72

    const int bt    = blockIdx.y;
    const int b     = bt >> 3;
    const int t     = bt & 7;
    const int itile = blockIdx.x;
    const int irow0 = itile * 16;
    const int lane  = threadIdx.x;      // = j within tile (score phase)
    const int l15   = lane & 15;
    const int quad  = lane >> 4;
    const int phase = itile & 15;

    f32x4 acc[4];
#pragma unroll
    for (int nc = 0; nc < 4; ++nc) acc[nc] = (f32x4){0.f, 0.f, 0.f, 0.f};
    float lsum[16], s1v[16];
#pragma unroll
    for (int r = 0; r < 16; ++r) {
        lsum[r] = 0.f;
        s1v[r]  = s1w[bt * N_NODES + irow0 + r];
    }

    const float*  adjrow = adj + (size_t)t * N_NODES * N_NODES
                               + (size_t)irow0 * N_NODES + lane;
    const __bf16* htb    = hF + (size_t)bt * 16 * 4096 + lane * 8;
    const float*  s2bt   = s2w + bt * N_NODES;
    __bf16* pwr = p_l + lane;                         // score write (lane = j)
    const __bf16* prd = p_l + l15 * 72 + quad * 8;    // P A-frag read

    // ---- preload tile `phase` ----
    float  adjc[16];
    bf16x8 hc[8];
    float  s2c;
    {
        const int jc0 = phase * 64;
#pragma unroll
        for (int r = 0; r < 16; ++r) adjc[r] = adjrow[(size_t)r * N_NODES + jc0];
        const __bf16* hp = htb + (size_t)phase * 4096;
#pragma unroll
        for (int c = 0; c < 8; ++c) hc[c] = *(const bf16x8*)(hp + c * 512);
        s2c = s2bt[jc0 + lane];
    }

#pragma unroll 2
    for (int it = 0; it < 16; ++it) {
        const int jt1 = (it + 1 + phase) & 15;   // next tile (ring)
        const int jn  = jt1 * 64;

        // ---- prefetch next tile ----
        float  adjn[16];
        bf16x8 hn[8];
#pragma unroll
        for (int r = 0; r < 16; ++r) adjn[r] = adjrow[(size_t)r * N_NODES + jn];
        const __bf16* hp = htb + (size_t)jt1 * 4096;
#pragma unroll
        for (int c = 0; c < 8; ++c) hn[c] = *(const bf16x8*)(hp + c * 512);
        const float s2n = s2bt[jn + lane];

        // ---- scores for current tile (lane = j); leaky bounds e*adj in
        // [-6,~16] so exp never overflows -> no max pass needed ----
#pragma unroll
        for (int r = 0; r < 16; ++r) {
            float e = s1v[r] + s2c;
            e = fmaxf(e, 0.2f * e);
            float p = (adjc[r] > 0.f) ? __expf(e * adjc[r]) : 0.f;
            lsum[r] += p;
            pwr[r * 72] = (__bf16)p;
        }

        // ---- P -> A-frag via wave-private LDS, then 8 MFMAs ----
        bf16x8 af0 = *(const bf16x8*)(prd);
        bf16x8 af1 = *(const bf16x8*)(prd + 32);
#pragma unroll
        for (int nc = 0; nc < 4; ++nc)
            acc[nc] = __builtin_amdgcn_mfma_f32_16x16x32_bf16(af0, hc[nc], acc[nc], 0, 0, 0);
#pragma unroll
        for (int nc = 0; nc < 4; ++nc)
            acc[nc] = __builtin_amdgcn_mfma_f32_16x16x32_bf16(af1, hc[4 + nc], acc[nc], 0, 0, 0);

        // ---- rotate prefetch buffers (unroll-2 renames the copies away) ----
#pragma unroll
        for (int r = 0; r < 16; ++r) adjc[r] = adjn[r];
#pragma unroll
        for (int c = 0; c < 8; ++c) hc[c] = hn[c];
        s2c = s2n;
    }

    // ---- epilogue: reduce lsum once, mi/ls scale + ELU + store ----
#pragma unroll
    for (int r = 0; r < 16; ++r) {
#pragma unroll
        for (int off = 32; off; off >>= 1)
            lsum[r] += __shfl_xor(lsum[r], off, 64);
    }
#pragma unroll
    for (int reg = 0; reg < 4; ++reg) {
        float ls = (quad == 0) ? lsum[reg] : (quad == 1) ? lsum[4 + reg]
                 : (quad == 2) ? lsum[8 + reg] : lsum[12 + reg];
        const int i = irow0 + quad * 4 + reg;
        float mi    = att_mask[((size_t)b * N_NODES + i) * T_DIM + t];
        float scale = mi / ls;
#pragma unroll
        for (int nc = 0; nc < 4; ++nc) {
            float v = acc[nc][reg] * scale;
            v = (v > 0.f) ? v : (__expf(v) - 1.f);
            out[((size_t)bt * N_NODES + i) * 64 + nc * 16 + l15] = v;
        }
    }
}

extern "C" void kernel_launch(void* const* d_in, const int* in_sizes, int n_in,
                              void* d_out, int out_size, void* d_ws, size_t ws_size,
                              hipStream_t stream) {
    (void)in_sizes; (void)n_in; (void)out_size; (void)ws_size;
    const float* adj      = (const float*)d_in[0];   // (T,N,N)
    const float* inp      = (const float*)d_in[1];   // (B,T,N,FI)
    const float* att_mask = (const float*)d_in[2];   // (B,N,T)
    const float* W        = (const float*)d_in[3];   // (FI,FO)
    const float* a        = (const float*)d_in[4];   // (2*FO,1)
    float* out = (float*)d_out;

    // ws: hF 4MB | s1 128KB | s2 128KB
    __bf16* hF  = (__bf16*)d_ws;
    float*  s1w = (float*)((char*)d_ws + (size_t)4 * 1024 * 1024);
    float*  s2w = s1w + 32 * N_NODES;

    gat_h_kernel<<<512, 256, 0, stream>>>(inp, W, a, att_mask, hF, s1w, s2w);
    dim3 grid(64, 32);
    gat_attn_kernel<<<grid, 64, 0, stream>>>(adj, att_mask, hF, s1w, s2w, out);
}

// Round 14
// 122.752 us; speedup vs baseline: 1.2203x; 1.0175x over previous
//
#include <hip/hip_runtime.h>
#include <hip/hip_bf16.h>
#include <math.h>

#define N_NODES 1024
#define T_DIM 8

typedef __bf16 bf16x8 __attribute__((ext_vector_type(8)));
typedef float  f32x4  __attribute__((ext_vector_type(4)));

__device__ __forceinline__ float readlane_f(float v, int l) {
    return __uint_as_float(__builtin_amdgcn_readlane(__float_as_uint(v), l));
}

// ---- Kernel A: h = inp@W ; s1,s2 ; hF = (h*mask_j) in B-frag-ordered tiles --
// hF tile (bt,jt) = 8 chunks of 1KB; chunk c=kc*4+nc, lane l, m 0..7 holds
// h[o = nc*16 + (l&15)][j = jt*64 + (l>>4)*8 + kc*32 + m] * mask_j.
// mask_j folded here (hF only feeds PV; softmax denominator is unmasked).
__global__ __launch_bounds__(256) void gat_h_kernel(
    const float* __restrict__ inp, const float* __restrict__ W,
    const float* __restrict__ a, const float* __restrict__ att_mask,
    __bf16* __restrict__ hF, float* __restrict__ s1w, float* __restrict__ s2w)
{
    __shared__ float Wl[64 * 64];
    __shared__ float xl[64 * 64];
    __shared__ __bf16 htl[64 * 72];   // [o][j], stride 72

    const int tid  = threadIdx.x;
    const int blk  = blockIdx.x;
    const int bt   = blk >> 4;
    const int b    = bt >> 3;
    const int t    = bt & 7;
    const int nt   = blk & 15;        // j-tile
    const int n0   = nt * 64;
    const int lane = tid & 63;        // = o in compute phase
    const int wave = tid >> 6;

    const float4* W4  = (const float4*)W;
    float4*       Wl4 = (float4*)Wl;
    const float4* x4  = (const float4*)(inp + (size_t)(bt * N_NODES + n0) * 64);
    float4*       xl4 = (float4*)xl;
#pragma unroll
    for (int k = 0; k < 4; ++k) {
        Wl4[tid + k * 256] = W4[tid + k * 256];
        xl4[tid + k * 256] = x4[tid + k * 256];
    }
    const float a1 = a[lane];
    const float a2 = a[64 + lane];
    __syncthreads();

#pragma unroll 1
    for (int rg = 0; rg < 16; rg += 4) {
        float xr[4], acc[4];
#pragma unroll
        for (int q = 0; q < 4; ++q) {
            xr[q]  = xl[(wave * 16 + rg + q) * 64 + lane];
            acc[q] = 0.f;
        }
#pragma unroll
        for (int f = 0; f < 64; ++f) {
            float w = Wl[f * 64 + lane];
#pragma unroll
            for (int q = 0; q < 4; ++q)
                acc[q] = fmaf(readlane_f(xr[q], f), w, acc[q]);
        }
#pragma unroll
        for (int q = 0; q < 4; ++q) {
            const int r = wave * 16 + rg + q;   // local j
            float v1 = acc[q] * a1, v2 = acc[q] * a2;
#pragma unroll
            for (int off = 32; off; off >>= 1) {
                v1 += __shfl_xor(v1, off, 64);
                v2 += __shfl_xor(v2, off, 64);
            }
            if (lane == 0) {
                s1w[bt * N_NODES + n0 + r] = v1;
                s2w[bt * N_NODES + n0 + r] = v2;
            }
            const float mjr = att_mask[((size_t)b * N_NODES + n0 + r) * T_DIM + t];
            htl[lane * 72 + r] = (__bf16)(acc[q] * mjr);   // [o][j]
        }
    }
    __syncthreads();

    // hF write: B-frag-ordered chunks (validated r10-r13)
    {
        const int l  = tid & 63;
        const int w  = tid >> 6;
        __bf16* tbase = hF + (size_t)(bt * 16 + nt) * 4096;
#pragma unroll
        for (int cc = 0; cc < 2; ++cc) {
            const int c  = w + cc * 4;       // chunk = kc*4 + nc
            const int nc = c & 3;
            const int kc = c >> 2;
            bf16x8 v = *(const bf16x8*)&htl[(nc * 16 + (l & 15)) * 72
                                            + (l >> 4) * 8 + kc * 32];
            *(bf16x8*)(tbase + (c * 64 + l) * 8) = v;
        }
    }
}

// ---- Kernel B: one-wave flash GAT — r13 body + 2-deep adj pipeline ----------
// grid (64 i-tiles, 32 bt) x 64 thr. adj (first-touch HBM latency ~900cy,
// beyond the ~700cy 1-ahead coverage) gets a 2-deep register pipeline;
// h (L2-resident hF tiles, 8 contiguous 1KB loads) and s2 stay 1-ahead.
// P via wave-private LDS; phase stagger itile&15 (b-siblings aligned -> adj
// L3 reuse). No barriers, no in-loop shuffles.
__global__ __launch_bounds__(64) void gat_attn_kernel(
    const float* __restrict__ adj, const float* __restrict__ att_mask,
    const __bf16* __restrict__ hF, const float* __restrict__ s1w,
    const float* __restrict__ s2w, float* __restrict__ out)
{
    __shared__ __align__(16) __bf16 p_l[16 * 72];   // [row][j], pad 72

    const int bt    = blockIdx.y;
    const int b     = bt >> 3;
    const int t     = bt & 7;
    const int itile = blockIdx.x;
    const int irow0 = itile * 16;
    const int lane  = threadIdx.x;      // = j within tile (score phase)
    const int l15   = lane & 15;
    const int quad  = lane >> 4;
    const int phase = itile & 15;

    f32x4 acc[4];
#pragma unroll
    for (int nc = 0; nc < 4; ++nc) acc[nc] = (f32x4){0.f, 0.f, 0.f, 0.f};
    float lsum[16], s1v[16];
#pragma unroll
    for (int r = 0; r < 16; ++r) {
        lsum[r] = 0.f;
        s1v[r]  = s1w[bt * N_NODES + irow0 + r];
    }

    const float*  adjrow = adj + (size_t)t * N_NODES * N_NODES
                               + (size_t)irow0 * N_NODES + lane;
    const __bf16* htb    = hF + (size_t)bt * 16 * 4096 + lane * 8;
    const float*  s2bt   = s2w + bt * N_NODES;
    __bf16* pwr = p_l + lane;                         // score write (lane = j)
    const __bf16* prd = p_l + l15 * 72 + quad * 8;    // P A-frag read

    // ---- preload: adj tiles phase, phase+1 (2-deep); h/s2 tile phase ----
    float  adj0[16], adj1[16];
    bf16x8 hc[8];
    float  s2c;
    {
        const int jc0 = phase * 64;
        const int jc1 = ((phase + 1) & 15) * 64;
#pragma unroll
        for (int r = 0; r < 16; ++r) {
            adj0[r] = adjrow[(size_t)r * N_NODES + jc0];
            adj1[r] = adjrow[(size_t)r * N_NODES + jc1];
        }
        const __bf16* hp = htb + (size_t)phase * 4096;
#pragma unroll
        for (int c = 0; c < 8; ++c) hc[c] = *(const bf16x8*)(hp + c * 512);
        s2c = s2bt[jc0 + lane];
    }

#pragma unroll 2
    for (int it = 0; it < 16; ++it) {
        const int jt1 = (it + 1 + phase) & 15;   // next tile (h/s2)
        const int jt2 = (it + 2 + phase) & 15;   // tile after (adj)

        // ---- prefetch: adj 2 ahead, h/s2 1 ahead ----
        float  adjn[16];
        bf16x8 hn[8];
#pragma unroll
        for (int r = 0; r < 16; ++r)
            adjn[r] = adjrow[(size_t)r * N_NODES + jt2 * 64];
        const __bf16* hp = htb + (size_t)jt1 * 4096;
#pragma unroll
        for (int c = 0; c < 8; ++c) hn[c] = *(const bf16x8*)(hp + c * 512);
        const float s2n = s2bt[jt1 * 64 + lane];

        // ---- scores for current tile (lane = j); leaky bounds e*adj in
        // [-6,~16] so exp never overflows -> no max pass needed ----
#pragma unroll
        for (int r = 0; r < 16; ++r) {
            float e = s1v[r] + s2c;
            e = fmaxf(e, 0.2f * e);
            float p = (adj0[r] > 0.f) ? __expf(e * adj0[r]) : 0.f;
            lsum[r] += p;
            pwr[r * 72] = (__bf16)p;
        }

        // ---- P -> A-frag via wave-private LDS, then 8 MFMAs ----
        bf16x8 af0 = *(const bf16x8*)(prd);
        bf16x8 af1 = *(const bf16x8*)(prd + 32);
#pragma unroll
        for (int nc = 0; nc < 4; ++nc)
            acc[nc] = __builtin_amdgcn_mfma_f32_16x16x32_bf16(af0, hc[nc], acc[nc], 0, 0, 0);
#pragma unroll
        for (int nc = 0; nc < 4; ++nc)
            acc[nc] = __builtin_amdgcn_mfma_f32_16x16x32_bf16(af1, hc[4 + nc], acc[nc], 0, 0, 0);

        // ---- shift pipelines (unroll-2 renames the copies away) ----
#pragma unroll
        for (int r = 0; r < 16; ++r) { adj0[r] = adj1[r]; adj1[r] = adjn[r]; }
#pragma unroll
        for (int c = 0; c < 8; ++c) hc[c] = hn[c];
        s2c = s2n;
    }

    // ---- epilogue: reduce lsum once, mi/ls scale + ELU + store ----
#pragma unroll
    for (int r = 0; r < 16; ++r) {
#pragma unroll
        for (int off = 32; off; off >>= 1)
            lsum[r] += __shfl_xor(lsum[r], off, 64);
    }
#pragma unroll
    for (int reg = 0; reg < 4; ++reg) {
        float ls = (quad == 0) ? lsum[reg] : (quad == 1) ? lsum[4 + reg]
                 : (quad == 2) ? lsum[8 + reg] : lsum[12 + reg];
        const int i = irow0 + quad * 4 + reg;
        float mi    = att_mask[((size_t)b * N_NODES + i) * T_DIM + t];
        float scale = mi / ls;
#pragma unroll
        for (int nc = 0; nc < 4; ++nc) {
            float v = acc[nc][reg] * scale;
            v = (v > 0.f) ? v : (__expf(v) - 1.f);
            out[((size_t)bt * N_NODES + i) * 64 + nc * 16 + l15] = v;
        }
    }
}

extern "C" void kernel_launch(void* const* d_in, const int* in_sizes, int n_in,
                              void* d_out, int out_size, void* d_ws, size_t ws_size,
                              hipStream_t stream) {
    (void)in_sizes; (void)n_in; (void)out_size; (void)ws_size;
    const float* adj      = (const float*)d_in[0];   // (T,N,N)
    const float* inp      = (const float*)d_in[1];   // (B,T,N,FI)
    const float* att_mask = (const float*)d_in[2];   // (B,N,T)
    const float* W        = (const float*)d_in[3];   // (FI,FO)
    const float* a        = (const float*)d_in[4];   // (2*FO,1)
    float* out = (float*)d_out;

    // ws: hF 4MB | s1 128KB | s2 128KB
    __bf16* hF  = (__bf16*)d_ws;
    float*  s1w = (float*)((char*)d_ws + (size_t)4 * 1024 * 1024);
    float*  s2w = s1w + 32 * N_NODES;

    gat_h_kernel<<<512, 256, 0, stream>>>(inp, W, a, att_mask, hF, s1w, s2w);
    dim3 grid(64, 32);
    gat_attn_kernel<<<grid, 64, 0, stream>>>(adj, att_mask, hF, s1w, s2w, out);
}